// Round 5
// baseline (48.413 us; speedup 1.0000x reference)
//
#include <hip/hip_runtime.h>
#include <cstdint>
#include <cstddef>

typedef short short8 __attribute__((ext_vector_type(8)));
typedef float f32x4 __attribute__((ext_vector_type(4)));

#define BB 16
#define SS 512
#define TT 64
#define LL 64
#define UU 128

// ws layout (bytes) — hi-only W fragments (no emb table)
#define WT_OFF    0u                      // W_trans frags: 32 x 1KB = 32KB
#define WHT_OFF   (WT_OFF + 32768u)       // W_ht frags: 64 x 1KB = 64KB
#define WREL_OFF  (WHT_OFF + 65536u)      // W_rel frags: 32 x 1KB = 32KB

__device__ __forceinline__ unsigned short f2bf(float x) {  // rtne f32->bf16
  unsigned u = __float_as_uint(x);
  unsigned r = ((u >> 16) & 1u) + 0x7FFFu;
  return (unsigned short)((u + r) >> 16);
}
__device__ __forceinline__ float ftanh(float x) {  // 1 - 2/(e^2x+1)
  float e = __expf(2.0f * x);
  return 1.0f - __fdividef(2.0f, e + 1.0f);
}
// packed rtne pair convert: lo=cvt(a), hi=cvt(b)
__device__ __forceinline__ unsigned cvtpk(float a, float b) {
  unsigned r;
  asm("v_cvt_pk_bf16_f32 %0, %1, %2" : "=v"(r) : "v"(a), "v"(b));
  return r;
}
// DPP ctrl must be an integer constant expression -> template parameter.
template<int CTRL>
__device__ __forceinline__ float dpp_mov(float x) {
  return __int_as_float(__builtin_amdgcn_update_dpp(
      0, __float_as_int(x), CTRL, 0xF, 0xF, true));
}
// 16-lane (DPP row) sum — pure VALU (verified numerically rounds 1-3).
__device__ __forceinline__ float row16_sum(float x) {
  x += dpp_mov<0xB1>(x);   // quad_perm xor1
  x += dpp_mov<0x4E>(x);   // quad_perm xor2
  x += dpp_mov<0x141>(x);  // row_half_mirror (xor4 once quads uniform)
  x += dpp_mov<0x140>(x);  // row_mirror (xor8 once 8-groups uniform)
  return x;
}
// full 64-lane reduces: row16 via DPP + cross-row via shfl_xor
__device__ __forceinline__ float full64_sum(float x) {
  x = row16_sum(x);
  x += __shfl_xor(x, 16, 64);
  x += __shfl_xor(x, 32, 64);
  return x;
}
__device__ __forceinline__ float full64_max(float x) {
  x = fmaxf(x, dpp_mov<0xB1>(x));
  x = fmaxf(x, dpp_mov<0x4E>(x));
  x = fmaxf(x, dpp_mov<0x141>(x));
  x = fmaxf(x, dpp_mov<0x140>(x));
  x = fmaxf(x, __shfl_xor(x, 16, 64));
  x = fmaxf(x, __shfl_xor(x, 32, 64));
  return x;
}

// ---- prep: pack W into bf16 fragments (hi only). 32 blocks, ~1.3us. -------
// Frag (16x16x32, A/B symmetric): lane l holds W[kt*32+(l>>4)*8+j][nt*16+(l&15)].
// pairIdx=(kt*8+nt): [pairIdx*1024 + lane*16].
__global__ void prep_kernel(const float* __restrict__ Wt,
                            const float* __restrict__ Wht,
                            const float* __restrict__ Wrel,
                            unsigned char* __restrict__ ws) {
  int slot = blockIdx.x * 256 + threadIdx.x;      // 8192 slots
  const float* W;
  unsigned char* base;
  if (slot < 2048)      { W = Wt;   base = ws + WT_OFF; }
  else if (slot < 6144) { W = Wht;  base = ws + WHT_OFF;  slot -= 2048; }
  else                  { W = Wrel; base = ws + WREL_OFF; slot -= 6144; }
  int lane = slot & 63, pair = slot >> 6;
  int n  = (pair & 7) * 16 + (lane & 15);
  int k0 = (pair >> 3) * 32 + (lane >> 4) * 8;
  short8 hv;
  #pragma unroll
  for (int j = 0; j < 8; ++j)
    hv[j] = (short)f2bf(W[(size_t)(k0 + j) * UU + n]);
  *reinterpret_cast<short8*>(base + (size_t)pair * 1024 + lane * 16) = hv;
}

// ---- fused per-(b,t) kernel: 1024 blocks x 1024 threads (16 waves) ---------
// R3-verified phase bodies; barrier count cut 9 -> 6:
//  - match-find moved post-staging (dedicated MATCH/NM LDS), overlaps GEMM1
//  - softmax computed redundantly per wave (DPP+shfl reduce), alpha via
//    wave-uniform readlane in wsum — no wave0 serialization, no ALPHA array
//  - scatter waves (w < nm) fold the PART 8-way reduce into their own reads
// Wave split: GEMM1 wave w -> (nt = w&7, row-half rh = w>>3); GEMM2 wave w ->
// (nt = w&7, m-pair mh = (w>>3)*2).  TEB swizzle: logical 16B-chunk c16 of
// row r at physical chunk c16^(r&15).
__launch_bounds__(1024, 8)
__global__ void fused_bt(const int* __restrict__ triples,
                         const float* __restrict__ emb_f32,
                         const float* __restrict__ b_trans,
                         const float* __restrict__ b_ht,
                         const float* __restrict__ b_rel,
                         const int* __restrict__ sent_triples,
                         const unsigned char* __restrict__ wsr,
                         float* __restrict__ out) {
  __shared__ unsigned short TEB[192 * 128];    // 48KB: emb staging -> te
  __shared__ float EWt[8][64];                 // e_weight partials
  __shared__ float PART[8][256];               // TOKs overlay (early) + partials
  __shared__ int MATCH[512];                   // dedicated (built during GEMM1)
  __shared__ int NM;
  int* TOKs = reinterpret_cast<int*>(&PART[0][0]);   // 768B of row 0

  const int tid  = threadIdx.x;
  const int bt   = blockIdx.x;
  const int w    = tid >> 6;      // wave id 0..15
  const int lane = tid & 63;
  const int li   = lane & 15;
  const int lg   = lane >> 4;
  const int nt   = w & 7;         // u-tile of 16
  const int rh   = w >> 3;        // 0/1

  // sent_triples prefetch: independent, issued at entry, used post-staging
  int sidx = -1;
  if (tid < SS) sidx = sent_triples[(size_t)(bt >> 6) * SS + tid];

  if (tid < 48)
    reinterpret_cast<int4*>(TOKs)[tid] =
        reinterpret_cast<const int4*>(triples + (size_t)bt * 192)[tid];
  if (tid == 1023) NM = 0;

  const unsigned char* wtb  = wsr + WT_OFF;
  const unsigned char* whtb = wsr + WHT_OFF;
  const unsigned char* wrlb = wsr + WREL_OFF;
  const float bhv   = b_ht[nt * 16 + li];
  const float brlv  = b_rel[nt * 16 + li];
  const float4 btr4 = *reinterpret_cast<const float4*>(b_trans + nt * 16 + lg * 4);
  __syncthreads();  // (b1) TOKs + NM ready

  // ---- stage ALL 192 emb rows into TEB (3 slots/thread, loads first) ----
  // f32 gather + in-flight cvt_pk to bf16; swizzle applied on source chunk.
  {
    float4 xv[3], yv[3];
    #pragma unroll
    for (int j = 0; j < 3; ++j) {
      int o = tid + j * 1024;             // 3072 slots = 192 rows x 16 chunks
      int row = o >> 4, pc = o & 15;
      int clog = pc ^ (row & 15);
      const float* fb = emb_f32 + (size_t)TOKs[row] * UU + clog * 8;
      xv[j] = *reinterpret_cast<const float4*>(fb);
      yv[j] = *reinterpret_cast<const float4*>(fb + 4);
    }
    #pragma unroll
    for (int j = 0; j < 3; ++j) {
      int o = tid + j * 1024;
      uint4 pk = { cvtpk(xv[j].x, xv[j].y), cvtpk(xv[j].z, xv[j].w),
                   cvtpk(yv[j].x, yv[j].y), cvtpk(yv[j].z, yv[j].w) };
      *reinterpret_cast<uint4*>(&TEB[o * 8]) = pk;
    }
  }

  // GEMM1 A-frags (W_trans^T), register-resident (hi only), loaded post-staging
  short8 B1h[4];
  #pragma unroll
  for (int kt = 0; kt < 4; ++kt)
    B1h[kt] = *reinterpret_cast<const short8*>(
        wtb + (size_t)(kt * 8 + nt) * 1024 + lane * 16);
  __syncthreads();  // (b2) staging complete

  // ---- match-find: overlaps GEMM1 (MATCH/NM not read until scatter) ------
  if (sidx == (bt & 63))
    MATCH[atomicAdd(&NM, 1)] = tid;

  const int cc8 = nt * 2 + (lg >> 1);  // u-chunk of this thread's u-quad
  const int hb8 = (lg & 1) << 3;       // byte offset within 16B chunk

  // ============ GEMM1 read phase: 6 tiles x 4 kt, barrier-free ============
  f32x4 acc[6];
  #pragma unroll
  for (int q = 0; q < 6; ++q) acc[q] = f32x4{0.f, 0.f, 0.f, 0.f};

  #pragma unroll
  for (int kt = 0; kt < 4; ++kt) {
    #pragma unroll
    for (int q = 0; q < 6; ++q) {
      // B-frag: lane reads emb row (rh*6+q)*16+li, k-chunk kt*4+lg
      const short8 b = *reinterpret_cast<const short8*>(
          &TEB[((rh * 6 + q) * 16 + li) * 128 + (((kt * 4 + lg) ^ li) << 3)]);
      acc[q] = __builtin_amdgcn_mfma_f32_16x16x32_bf16(B1h[kt], b, acc[q], 0, 0, 0);
    }
  }
  __syncthreads();  // (b3) ALL emb reads complete before any te overwrite

  // ============ GEMM1 write phase: te in one pass =========================
  #pragma unroll
  for (int q = 0; q < 6; ++q) {
    int row = (rh * 6 + q) * 16 + li;    // row & 15 == li
    float v0 = ftanh(acc[q][0] + btr4.x);
    float v1 = ftanh(acc[q][1] + btr4.y);
    float v2 = ftanh(acc[q][2] + btr4.z);
    float v3 = ftanh(acc[q][3] + btr4.w);
    uint2 pk = { cvtpk(v0, v1), cvtpk(v2, v3) };
    *reinterpret_cast<uint2*>(
        reinterpret_cast<char*>(TEB) + row * 256 +
        (((cc8 ^ li) << 4) | hb8)) = pk;
  }

  // prefetch GEMM2 first W-frag before the barrier
  short8 Wc = *reinterpret_cast<const short8*>(
      whtb + (size_t)nt * 1024 + lane * 16);
  __syncthreads();  // (b4) te complete

  // ============ GEMM2: ht_t / rel_t / e_weight (2 m-tiles per wave) =======
  // head = te row 3l+0, rel = 3l+1, tail = 3l+2  (l = m*16 + li)
  const int mh = rh * 2;
  f32x4 accH[2] = {{0.f,0.f,0.f,0.f},{0.f,0.f,0.f,0.f}};
  f32x4 accR[2] = {{0.f,0.f,0.f,0.f},{0.f,0.f,0.f,0.f}};

  #pragma unroll
  for (int kt = 0; kt < 8; ++kt) {   // head_tail: K=256
    short8 Wn;
    if (kt < 7)
      Wn = *reinterpret_cast<const short8*>(
          whtb + (size_t)((kt + 1) * 8 + nt) * 1024 + lane * 16);
    else
      Wn = *reinterpret_cast<const short8*>(
          wrlb + (size_t)nt * 1024 + lane * 16);
    const int koff = (kt < 4) ? 0 : 2;
    const int c16  = (kt & 3) * 4 + lg;
    #pragma unroll
    for (int mi = 0; mi < 2; ++mi) {
      const int row = 48 * (mh + mi) + 3 * li + koff;
      const short8 a = *reinterpret_cast<const short8*>(
          &TEB[row * 128 + ((c16 ^ (row & 15)) << 3)]);
      accH[mi] = __builtin_amdgcn_mfma_f32_16x16x32_bf16(a, Wc, accH[mi], 0, 0, 0);
    }
    Wc = Wn;
  }
  #pragma unroll
  for (int kt = 0; kt < 4; ++kt) {   // relation: K=128, rows 3l+1
    short8 Wn;
    if (kt < 3)
      Wn = *reinterpret_cast<const short8*>(
          wrlb + (size_t)((kt + 1) * 8 + nt) * 1024 + lane * 16);
    const int c16 = kt * 4 + lg;
    #pragma unroll
    for (int mi = 0; mi < 2; ++mi) {
      const int row = 48 * (mh + mi) + 3 * li + 1;
      const short8 a = *reinterpret_cast<const short8*>(
          &TEB[row * 128 + ((c16 ^ (row & 15)) << 3)]);
      accR[mi] = __builtin_amdgcn_mfma_f32_16x16x32_bf16(a, Wc, accR[mi], 0, 0, 0);
    }
    Wc = Wn;
  }

  // e_weight partials: l = (mh+mi)*16 + lg*4 + r; DPP-reduce over 16 u lanes
  #pragma unroll
  for (int mi = 0; mi < 2; ++mi) {
    #pragma unroll
    for (int r = 0; r < 4; ++r) {
      float p = ftanh(accH[mi][r] + bhv) * (accR[mi][r] + brlv);
      p = row16_sum(p);
      if (li == 0) EWt[nt][(mh + mi) * 16 + lg * 4 + r] = p;
    }
  }
  __syncthreads();  // (b5) EWt ready

  // ============ redundant softmax (every wave; no barrier after) ==========
  float alpha;
  {
    float e = 0.f;
    #pragma unroll
    for (int n = 0; n < 8; ++n) e += EWt[n][lane];   // stride-1, conflict-free
    float mx = full64_max(e);
    float ex = __expf(e - mx);
    float sm = full64_sum(ex);
    alpha = ex / sm;            // this lane holds alpha[l = lane]
  }

  // ============ weighted sum: paired-bf16 b32 reads, 8 l's per thread ======
  {
    int cp  = tid & 127, lgp = w >> 1;     // lgp = tid>>7, wave-uniform
    int c0  = cp << 1;
    int k   = (c0 >> 7) << 1;              // head rows 3l, tail rows 3l+2
    int cc  = c0 & 127;
    int w8  = cc >> 3, bofs = (cc & 7) << 1;
    float o0 = 0.f, o1 = 0.f;
    #pragma unroll
    for (int j = 0; j < 8; ++j) {
      int l = lgp * 8 + j;
      float al = __int_as_float(
          __builtin_amdgcn_readlane(__float_as_int(alpha), l));  // uniform lane
      int row = 3 * l + k;
      unsigned u = *reinterpret_cast<const unsigned*>(
          reinterpret_cast<const char*>(TEB) + row * 256 +
          (((w8 ^ (row & 15)) << 4) | bofs));
      o0 = fmaf(al, __uint_as_float(u << 16), o0);
      o1 = fmaf(al, __uint_as_float(u & 0xFFFF0000u), o1);
    }
    *reinterpret_cast<float2*>(&PART[lgp][c0]) = make_float2(o0, o1);
  }
  __syncthreads();  // (b6) PART ready; MATCH/NM final since GEMM1

  // ============ scatter: participating waves fold the 8-way reduce ========
  {
    const int b  = bt >> 6;
    const int nm = NM;
    if (w < nm) {
      float4 v = {0.f, 0.f, 0.f, 0.f};
      #pragma unroll
      for (int g = 0; g < 8; ++g) {
        float4 p = reinterpret_cast<const float4*>(&PART[g][0])[lane];
        v.x += p.x; v.y += p.y; v.z += p.z; v.w += p.w;
      }
      for (int q = w; q < nm; q += 16) {
        int s = MATCH[q];
        reinterpret_cast<float4*>(out + ((size_t)(b * SS + s)) * 256)[lane] = v;
      }
    }
  }
}

extern "C" void kernel_launch(void* const* d_in, const int* in_sizes, int n_in,
                              void* d_out, int out_size, void* d_ws, size_t ws_size,
                              hipStream_t stream) {
  const int*   triples      = (const int*)d_in[1];
  const int*   sent_triples = (const int*)d_in[2];
  const float* emb_table    = (const float*)d_in[3];
  const float* W_trans      = (const float*)d_in[4];
  const float* b_trans      = (const float*)d_in[5];
  const float* W_ht         = (const float*)d_in[6];
  const float* b_ht         = (const float*)d_in[7];
  const float* W_rel        = (const float*)d_in[8];
  const float* b_rel        = (const float*)d_in[9];
  float* out = (float*)d_out;
  unsigned char* ws = (unsigned char*)d_ws;

  prep_kernel<<<32, 256, 0, stream>>>(W_trans, W_ht, W_rel, ws);

  fused_bt<<<BB * TT, 1024, 0, stream>>>(
      triples, emb_table, b_trans, b_ht, b_rel, sent_triples, ws, out);
}

// Round 6
// 48.211 us; speedup vs baseline: 1.0042x; 1.0042x over previous
//
#include <hip/hip_runtime.h>
#include <cstdint>
#include <cstddef>

typedef short short8 __attribute__((ext_vector_type(8)));
typedef float f32x4 __attribute__((ext_vector_type(4)));

#define BB 16
#define SS 512
#define TT 64
#define LL 64
#define UU 128

// ws layout (bytes) — hi-only W fragments (no emb table)
#define WT_OFF    0u                      // W_trans frags: 32 x 1KB = 32KB
#define WHT_OFF   (WT_OFF + 32768u)       // W_ht frags: 64 x 1KB = 64KB
#define WREL_OFF  (WHT_OFF + 65536u)      // W_rel frags: 32 x 1KB = 32KB

__device__ __forceinline__ unsigned short f2bf(float x) {  // rtne f32->bf16
  unsigned u = __float_as_uint(x);
  unsigned r = ((u >> 16) & 1u) + 0x7FFFu;
  return (unsigned short)((u + r) >> 16);
}
__device__ __forceinline__ float ftanh(float x) {  // 1 - 2/(e^2x+1)
  float e = __expf(2.0f * x);
  return 1.0f - __fdividef(2.0f, e + 1.0f);
}
// packed rtne pair convert: lo=cvt(a), hi=cvt(b)
__device__ __forceinline__ unsigned cvtpk(float a, float b) {
  unsigned r;
  asm("v_cvt_pk_bf16_f32 %0, %1, %2" : "=v"(r) : "v"(a), "v"(b));
  return r;
}
// DPP ctrl must be an integer constant expression -> template parameter.
template<int CTRL>
__device__ __forceinline__ float dpp_mov(float x) {
  return __int_as_float(__builtin_amdgcn_update_dpp(
      0, __float_as_int(x), CTRL, 0xF, 0xF, true));
}
// 16-lane (DPP row) sum — pure VALU (verified numerically rounds 1-5).
__device__ __forceinline__ float row16_sum(float x) {
  x += dpp_mov<0xB1>(x);   // quad_perm xor1
  x += dpp_mov<0x4E>(x);   // quad_perm xor2
  x += dpp_mov<0x141>(x);  // row_half_mirror (xor4 once quads uniform)
  x += dpp_mov<0x140>(x);  // row_mirror (xor8 once 8-groups uniform)
  return x;
}
// full 64-lane reduces: row16 via DPP + cross-row via shfl_xor
__device__ __forceinline__ float full64_sum(float x) {
  x = row16_sum(x);
  x += __shfl_xor(x, 16, 64);
  x += __shfl_xor(x, 32, 64);
  return x;
}
__device__ __forceinline__ float full64_max(float x) {
  x = fmaxf(x, dpp_mov<0xB1>(x));
  x = fmaxf(x, dpp_mov<0x4E>(x));
  x = fmaxf(x, dpp_mov<0x141>(x));
  x = fmaxf(x, dpp_mov<0x140>(x));
  x = fmaxf(x, __shfl_xor(x, 16, 64));
  x = fmaxf(x, __shfl_xor(x, 32, 64));
  return x;
}

// ---- prep: pack W into bf16 fragments (hi only). 32 blocks, ~1.3us. -------
// Frag (16x16x32, A/B symmetric): lane l holds W[kt*32+(l>>4)*8+j][nt*16+(l&15)].
// pairIdx=(kt*8+nt): [pairIdx*1024 + lane*16].
__global__ void prep_kernel(const float* __restrict__ Wt,
                            const float* __restrict__ Wht,
                            const float* __restrict__ Wrel,
                            unsigned char* __restrict__ ws) {
  int slot = blockIdx.x * 256 + threadIdx.x;      // 8192 slots
  const float* W;
  unsigned char* base;
  if (slot < 2048)      { W = Wt;   base = ws + WT_OFF; }
  else if (slot < 6144) { W = Wht;  base = ws + WHT_OFF;  slot -= 2048; }
  else                  { W = Wrel; base = ws + WREL_OFF; slot -= 6144; }
  int lane = slot & 63, pair = slot >> 6;
  int n  = (pair & 7) * 16 + (lane & 15);
  int k0 = (pair >> 3) * 32 + (lane >> 4) * 8;
  short8 hv;
  #pragma unroll
  for (int j = 0; j < 8; ++j)
    hv[j] = (short)f2bf(W[(size_t)(k0 + j) * UU + n]);
  *reinterpret_cast<short8*>(base + (size_t)pair * 1024 + lane * 16) = hv;
}

// ---- fused per-(b,t) kernel: 1024 blocks x 1024 threads (16 waves) ---------
// R5 structure, entry latency chain removed (barriers 6 -> 5):
//  - per-thread DIRECT token loads (3 broadcast-coalesced b32, L2-resident)
//    replace the TOKs LDS round-trip + its barrier; emb gathers issue within
//    ~30 cycles of block start
//  - B1h ws-loads hoisted before the TEB staging writes (latency overlap)
// Wave split: GEMM1 wave w -> (nt = w&7, row-half rh = w>>3); GEMM2 wave w ->
// (nt = w&7, m-pair mh = (w>>3)*2).  TEB swizzle: logical 16B-chunk c16 of
// row r at physical chunk c16^(r&15).
__launch_bounds__(1024, 8)
__global__ void fused_bt(const int* __restrict__ triples,
                         const float* __restrict__ emb_f32,
                         const float* __restrict__ b_trans,
                         const float* __restrict__ b_ht,
                         const float* __restrict__ b_rel,
                         const int* __restrict__ sent_triples,
                         const unsigned char* __restrict__ wsr,
                         float* __restrict__ out) {
  __shared__ unsigned short TEB[192 * 128];    // 48KB: emb staging -> te
  __shared__ float EWt[8][64];                 // e_weight partials
  __shared__ float PART[8][256];               // wsum partials (8 l-groups)
  __shared__ int MATCH[512];                   // dedicated (built during GEMM1)
  __shared__ int NM;

  const int tid  = threadIdx.x;
  const int bt   = blockIdx.x;
  const int w    = tid >> 6;      // wave id 0..15
  const int lane = tid & 63;
  const int li   = lane & 15;
  const int lg   = lane >> 4;
  const int nt   = w & 7;         // u-tile of 16
  const int rh   = w >> 3;        // 0/1

  // ---- stage ALL 192 emb rows into TEB: tokens loaded per-thread (no LDS
  // round-trip, no barrier) so the f32 gathers issue immediately. ----------
  int tok[3];
  #pragma unroll
  for (int j = 0; j < 3; ++j) {
    int row = (tid + j * 1024) >> 4;    // 16 adjacent threads share a row
    tok[j] = triples[(size_t)bt * 192 + row];
  }
  // sent_triples prefetch: independent, issued at entry, used post-staging
  int sidx = -1;
  if (tid < SS) sidx = sent_triples[(size_t)(bt >> 6) * SS + tid];
  if (tid == 0) NM = 0;

  float4 xv[3], yv[3];
  #pragma unroll
  for (int j = 0; j < 3; ++j) {
    int o = tid + j * 1024;             // 3072 slots = 192 rows x 16 chunks
    int row = o >> 4, pc = o & 15;
    int clog = pc ^ (row & 15);
    const float* fb = emb_f32 + (size_t)tok[j] * UU + clog * 8;
    xv[j] = *reinterpret_cast<const float4*>(fb);
    yv[j] = *reinterpret_cast<const float4*>(fb + 4);
  }

  // GEMM1 A-frags (W_trans^T): issue BEFORE the TEB writes so their L2
  // latency hides under the cvt+store work.
  const unsigned char* wtb  = wsr + WT_OFF;
  const unsigned char* whtb = wsr + WHT_OFF;
  const unsigned char* wrlb = wsr + WREL_OFF;
  short8 B1h[4];
  #pragma unroll
  for (int kt = 0; kt < 4; ++kt)
    B1h[kt] = *reinterpret_cast<const short8*>(
        wtb + (size_t)(kt * 8 + nt) * 1024 + lane * 16);

  #pragma unroll
  for (int j = 0; j < 3; ++j) {
    int o = tid + j * 1024;
    uint4 pk = { cvtpk(xv[j].x, xv[j].y), cvtpk(xv[j].z, xv[j].w),
                 cvtpk(yv[j].x, yv[j].y), cvtpk(yv[j].z, yv[j].w) };
    *reinterpret_cast<uint4*>(&TEB[o * 8]) = pk;
  }

  const float bhv   = b_ht[nt * 16 + li];
  const float brlv  = b_rel[nt * 16 + li];
  const float4 btr4 = *reinterpret_cast<const float4*>(b_trans + nt * 16 + lg * 4);
  __syncthreads();  // (b2) staging complete; NM=0 visible

  // ---- match-find: overlaps GEMM1 (MATCH/NM not read until scatter) ------
  if (sidx == (bt & 63))
    MATCH[atomicAdd(&NM, 1)] = tid;

  const int cc8 = nt * 2 + (lg >> 1);  // u-chunk of this thread's u-quad
  const int hb8 = (lg & 1) << 3;       // byte offset within 16B chunk

  // ============ GEMM1 read phase: 6 tiles x 4 kt, barrier-free ============
  f32x4 acc[6];
  #pragma unroll
  for (int q = 0; q < 6; ++q) acc[q] = f32x4{0.f, 0.f, 0.f, 0.f};

  #pragma unroll
  for (int kt = 0; kt < 4; ++kt) {
    #pragma unroll
    for (int q = 0; q < 6; ++q) {
      // B-frag: lane reads emb row (rh*6+q)*16+li, k-chunk kt*4+lg
      const short8 b = *reinterpret_cast<const short8*>(
          &TEB[((rh * 6 + q) * 16 + li) * 128 + (((kt * 4 + lg) ^ li) << 3)]);
      acc[q] = __builtin_amdgcn_mfma_f32_16x16x32_bf16(B1h[kt], b, acc[q], 0, 0, 0);
    }
  }
  __syncthreads();  // (b3) ALL emb reads complete before any te overwrite

  // ============ GEMM1 write phase: te in one pass =========================
  #pragma unroll
  for (int q = 0; q < 6; ++q) {
    int row = (rh * 6 + q) * 16 + li;    // row & 15 == li
    float v0 = ftanh(acc[q][0] + btr4.x);
    float v1 = ftanh(acc[q][1] + btr4.y);
    float v2 = ftanh(acc[q][2] + btr4.z);
    float v3 = ftanh(acc[q][3] + btr4.w);
    uint2 pk = { cvtpk(v0, v1), cvtpk(v2, v3) };
    *reinterpret_cast<uint2*>(
        reinterpret_cast<char*>(TEB) + row * 256 +
        (((cc8 ^ li) << 4) | hb8)) = pk;
  }

  // prefetch GEMM2 first W-frag before the barrier
  short8 Wc = *reinterpret_cast<const short8*>(
      whtb + (size_t)nt * 1024 + lane * 16);
  __syncthreads();  // (b4) te complete

  // ============ GEMM2: ht_t / rel_t / e_weight (2 m-tiles per wave) =======
  // head = te row 3l+0, rel = 3l+1, tail = 3l+2  (l = m*16 + li)
  const int mh = rh * 2;
  f32x4 accH[2] = {{0.f,0.f,0.f,0.f},{0.f,0.f,0.f,0.f}};
  f32x4 accR[2] = {{0.f,0.f,0.f,0.f},{0.f,0.f,0.f,0.f}};

  #pragma unroll
  for (int kt = 0; kt < 8; ++kt) {   // head_tail: K=256
    short8 Wn;
    if (kt < 7)
      Wn = *reinterpret_cast<const short8*>(
          whtb + (size_t)((kt + 1) * 8 + nt) * 1024 + lane * 16);
    else
      Wn = *reinterpret_cast<const short8*>(
          wrlb + (size_t)nt * 1024 + lane * 16);
    const int koff = (kt < 4) ? 0 : 2;
    const int c16  = (kt & 3) * 4 + lg;
    #pragma unroll
    for (int mi = 0; mi < 2; ++mi) {
      const int row = 48 * (mh + mi) + 3 * li + koff;
      const short8 a = *reinterpret_cast<const short8*>(
          &TEB[row * 128 + ((c16 ^ (row & 15)) << 3)]);
      accH[mi] = __builtin_amdgcn_mfma_f32_16x16x32_bf16(a, Wc, accH[mi], 0, 0, 0);
    }
    Wc = Wn;
  }
  #pragma unroll
  for (int kt = 0; kt < 4; ++kt) {   // relation: K=128, rows 3l+1
    short8 Wn;
    if (kt < 3)
      Wn = *reinterpret_cast<const short8*>(
          wrlb + (size_t)((kt + 1) * 8 + nt) * 1024 + lane * 16);
    const int c16 = kt * 4 + lg;
    #pragma unroll
    for (int mi = 0; mi < 2; ++mi) {
      const int row = 48 * (mh + mi) + 3 * li + 1;
      const short8 a = *reinterpret_cast<const short8*>(
          &TEB[row * 128 + ((c16 ^ (row & 15)) << 3)]);
      accR[mi] = __builtin_amdgcn_mfma_f32_16x16x32_bf16(a, Wc, accR[mi], 0, 0, 0);
    }
    Wc = Wn;
  }

  // e_weight partials: l = (mh+mi)*16 + lg*4 + r; DPP-reduce over 16 u lanes
  #pragma unroll
  for (int mi = 0; mi < 2; ++mi) {
    #pragma unroll
    for (int r = 0; r < 4; ++r) {
      float p = ftanh(accH[mi][r] + bhv) * (accR[mi][r] + brlv);
      p = row16_sum(p);
      if (li == 0) EWt[nt][(mh + mi) * 16 + lg * 4 + r] = p;
    }
  }
  __syncthreads();  // (b5) EWt ready

  // ============ redundant softmax (every wave; no barrier after) ==========
  float alpha;
  {
    float e = 0.f;
    #pragma unroll
    for (int n = 0; n < 8; ++n) e += EWt[n][lane];   // stride-1, conflict-free
    float mx = full64_max(e);
    float ex = __expf(e - mx);
    float sm = full64_sum(ex);
    alpha = ex / sm;            // this lane holds alpha[l = lane]
  }

  // ============ weighted sum: paired-bf16 b32 reads, 8 l's per thread ======
  {
    int cp  = tid & 127, lgp = w >> 1;     // lgp = tid>>7, wave-uniform
    int c0  = cp << 1;
    int k   = (c0 >> 7) << 1;              // head rows 3l, tail rows 3l+2
    int cc  = c0 & 127;
    int w8  = cc >> 3, bofs = (cc & 7) << 1;
    float o0 = 0.f, o1 = 0.f;
    #pragma unroll
    for (int j = 0; j < 8; ++j) {
      int l = lgp * 8 + j;
      float al = __int_as_float(
          __builtin_amdgcn_readlane(__float_as_int(alpha), l));  // uniform lane
      int row = 3 * l + k;
      unsigned u = *reinterpret_cast<const unsigned*>(
          reinterpret_cast<const char*>(TEB) + row * 256 +
          (((w8 ^ (row & 15)) << 4) | bofs));
      o0 = fmaf(al, __uint_as_float(u << 16), o0);
      o1 = fmaf(al, __uint_as_float(u & 0xFFFF0000u), o1);
    }
    *reinterpret_cast<float2*>(&PART[lgp][c0]) = make_float2(o0, o1);
  }
  __syncthreads();  // (b6) PART ready; MATCH/NM final since GEMM1

  // ============ scatter: participating waves fold the 8-way reduce ========
  {
    const int b  = bt >> 6;
    const int nm = NM;
    if (w < nm) {
      float4 v = {0.f, 0.f, 0.f, 0.f};
      #pragma unroll
      for (int g = 0; g < 8; ++g) {
        float4 p = reinterpret_cast<const float4*>(&PART[g][0])[lane];
        v.x += p.x; v.y += p.y; v.z += p.z; v.w += p.w;
      }
      for (int q = w; q < nm; q += 16) {
        int s = MATCH[q];
        reinterpret_cast<float4*>(out + ((size_t)(b * SS + s)) * 256)[lane] = v;
      }
    }
  }
}

extern "C" void kernel_launch(void* const* d_in, const int* in_sizes, int n_in,
                              void* d_out, int out_size, void* d_ws, size_t ws_size,
                              hipStream_t stream) {
  const int*   triples      = (const int*)d_in[1];
  const int*   sent_triples = (const int*)d_in[2];
  const float* emb_table    = (const float*)d_in[3];
  const float* W_trans      = (const float*)d_in[4];
  const float* b_trans      = (const float*)d_in[5];
  const float* W_ht         = (const float*)d_in[6];
  const float* b_ht         = (const float*)d_in[7];
  const float* W_rel        = (const float*)d_in[8];
  const float* b_rel        = (const float*)d_in[9];
  float* out = (float*)d_out;
  unsigned char* ws = (unsigned char*)d_ws;

  prep_kernel<<<32, 256, 0, stream>>>(W_trans, W_ht, W_rel, ws);

  fused_bt<<<BB * TT, 1024, 0, stream>>>(
      triples, emb_table, b_trans, b_ht, b_rel, sent_triples, ws, out);
}

// Round 7
// 43.359 us; speedup vs baseline: 1.1165x; 1.1119x over previous
//
#include <hip/hip_runtime.h>
#include <cstdint>
#include <cstddef>

typedef short short8 __attribute__((ext_vector_type(8)));
typedef float f32x4 __attribute__((ext_vector_type(4)));

#define BB 16
#define SS 512
#define TT 64
#define LL 64
#define UU 128
#define NV 40000

// ws layout (bytes)
#define WT_OFF    0u                      // W_trans frags: 32 x 1KB = 32KB
#define WHT_OFF   (WT_OFF + 32768u)       // W_ht frags: 64 x 1KB = 64KB
#define WREL_OFF  (WHT_OFF + 65536u)      // W_rel frags: 32 x 1KB = 32KB
#define TE_OFF    (WREL_OFF + 32768u)     // te table: 40000 x 128 bf16 = 10.24MB

__device__ __forceinline__ unsigned short f2bf(float x) {  // rtne f32->bf16
  unsigned u = __float_as_uint(x);
  unsigned r = ((u >> 16) & 1u) + 0x7FFFu;
  return (unsigned short)((u + r) >> 16);
}
__device__ __forceinline__ float ftanh(float x) {  // 1 - 2/(e^2x+1)
  float e = __expf(2.0f * x);
  return 1.0f - __fdividef(2.0f, e + 1.0f);
}
// packed rtne pair convert: lo=cvt(a), hi=cvt(b)
__device__ __forceinline__ unsigned cvtpk(float a, float b) {
  unsigned r;
  asm("v_cvt_pk_bf16_f32 %0, %1, %2" : "=v"(r) : "v"(a), "v"(b));
  return r;
}
// DPP ctrl must be an integer constant expression -> template parameter.
template<int CTRL>
__device__ __forceinline__ float dpp_mov(float x) {
  return __int_as_float(__builtin_amdgcn_update_dpp(
      0, __float_as_int(x), CTRL, 0xF, 0xF, true));
}
// 16-lane (DPP row) sum — pure VALU (verified numerically rounds 1-6).
__device__ __forceinline__ float row16_sum(float x) {
  x += dpp_mov<0xB1>(x);
  x += dpp_mov<0x4E>(x);
  x += dpp_mov<0x141>(x);
  x += dpp_mov<0x140>(x);
  return x;
}
__device__ __forceinline__ float full64_sum(float x) {
  x = row16_sum(x);
  x += __shfl_xor(x, 16, 64);
  x += __shfl_xor(x, 32, 64);
  return x;
}
__device__ __forceinline__ float full64_max(float x) {
  x = fmaxf(x, dpp_mov<0xB1>(x));
  x = fmaxf(x, dpp_mov<0x4E>(x));
  x = fmaxf(x, dpp_mov<0x141>(x));
  x = fmaxf(x, dpp_mov<0x140>(x));
  x = fmaxf(x, __shfl_xor(x, 16, 64));
  x = fmaxf(x, __shfl_xor(x, 32, 64));
  return x;
}

// ---- prep A: pack W into bf16 fragments (hi only). 32 blocks. -------------
// Frag (16x16x32, A/B symmetric): lane l holds W[kt*32+(l>>4)*8+j][nt*16+(l&15)].
// pairIdx=(kt*8+nt): [pairIdx*1024 + lane*16].
__global__ void prep_kernel(const float* __restrict__ Wt,
                            const float* __restrict__ Wht,
                            const float* __restrict__ Wrel,
                            unsigned char* __restrict__ ws) {
  int slot = blockIdx.x * 256 + threadIdx.x;      // 8192 slots
  const float* W;
  unsigned char* base;
  if (slot < 2048)      { W = Wt;   base = ws + WT_OFF; }
  else if (slot < 6144) { W = Wht;  base = ws + WHT_OFF;  slot -= 2048; }
  else                  { W = Wrel; base = ws + WREL_OFF; slot -= 6144; }
  int lane = slot & 63, pair = slot >> 6;
  int n  = (pair & 7) * 16 + (lane & 15);
  int k0 = (pair >> 3) * 32 + (lane >> 4) * 8;
  short8 hv;
  #pragma unroll
  for (int j = 0; j < 8; ++j)
    hv[j] = (short)f2bf(W[(size_t)(k0 + j) * UU + n]);
  *reinterpret_cast<short8*>(base + (size_t)pair * 1024 + lane * 16) = hv;
}

// ---- prep B: te table over the whole vocab --------------------------------
// te[v] = tanh(emb[v] @ W_trans + b_trans), bf16.  Numerics identical to the
// old in-block GEMM1 (same staging cvt, same MFMA, same epilogue math).
// 209 blocks x 1024 threads, 192 consecutive vocab rows each (clamped).
__launch_bounds__(1024, 8)
__global__ void prep_te(const float* __restrict__ emb_f32,
                        const float* __restrict__ b_trans,
                        const unsigned char* __restrict__ wsr,
                        unsigned short* __restrict__ te_g) {
  __shared__ unsigned short TEB[192 * 128];
  const int tid  = threadIdx.x;
  const int base = blockIdx.x * 192;
  const int w    = tid >> 6;
  const int lane = tid & 63;
  const int li   = lane & 15;
  const int lg   = lane >> 4;
  const int nt   = w & 7;
  const int rh   = w >> 3;

  // stage 192 consecutive emb rows (f32 -> bf16, swizzled) — coalesced
  float4 xv[3], yv[3];
  #pragma unroll
  for (int j = 0; j < 3; ++j) {
    int o = tid + j * 1024, row = o >> 4, pc = o & 15;
    int grow = base + row; if (grow > NV - 1) grow = NV - 1;
    int clog = pc ^ (row & 15);
    const float* fb = emb_f32 + (size_t)grow * UU + clog * 8;
    xv[j] = *reinterpret_cast<const float4*>(fb);
    yv[j] = *reinterpret_cast<const float4*>(fb + 4);
  }
  const unsigned char* wtb = wsr + WT_OFF;
  short8 B1h[4];
  #pragma unroll
  for (int kt = 0; kt < 4; ++kt)
    B1h[kt] = *reinterpret_cast<const short8*>(
        wtb + (size_t)(kt * 8 + nt) * 1024 + lane * 16);
  #pragma unroll
  for (int j = 0; j < 3; ++j) {
    int o = tid + j * 1024;
    uint4 pk = { cvtpk(xv[j].x, xv[j].y), cvtpk(xv[j].z, xv[j].w),
                 cvtpk(yv[j].x, yv[j].y), cvtpk(yv[j].z, yv[j].w) };
    *reinterpret_cast<uint4*>(&TEB[o * 8]) = pk;
  }
  const float4 btr4 = *reinterpret_cast<const float4*>(b_trans + nt * 16 + lg * 4);
  __syncthreads();

  // GEMM1 (verbatim): 6 row-tiles x 4 kt per wave
  f32x4 acc[6];
  #pragma unroll
  for (int q = 0; q < 6; ++q) acc[q] = f32x4{0.f, 0.f, 0.f, 0.f};
  #pragma unroll
  for (int kt = 0; kt < 4; ++kt) {
    #pragma unroll
    for (int q = 0; q < 6; ++q) {
      const short8 b = *reinterpret_cast<const short8*>(
          &TEB[((rh * 6 + q) * 16 + li) * 128 + (((kt * 4 + lg) ^ li) << 3)]);
      acc[q] = __builtin_amdgcn_mfma_f32_16x16x32_bf16(B1h[kt], b, acc[q], 0, 0, 0);
    }
  }

  // epilogue: tanh + bias, write bf16 pairs straight to the global table.
  // D layout: te-row = li (col idx), u = nt*16 + lg*4 + r.
  #pragma unroll
  for (int q = 0; q < 6; ++q) {
    int row  = (rh * 6 + q) * 16 + li;
    int grow = base + row; if (grow > NV - 1) grow = NV - 1;  // dup write, same value
    float v0 = ftanh(acc[q][0] + btr4.x);
    float v1 = ftanh(acc[q][1] + btr4.y);
    float v2 = ftanh(acc[q][2] + btr4.z);
    float v3 = ftanh(acc[q][3] + btr4.w);
    uint2 pk = { cvtpk(v0, v1), cvtpk(v2, v3) };
    *reinterpret_cast<uint2*>(te_g + (size_t)grow * UU + nt * 16 + lg * 4) = pk;
  }
}

// ---- fused per-(b,t) kernel: 1024 blocks x 1024 threads (16 waves) ---------
// GEMM1 hoisted to prep_te: block now gathers PRE-TRANSFORMED te rows (bf16)
// into TEB and goes straight to GEMM2.  Barriers: 3 (staging / EWt / PART).
// GEMM2 wave split: nt = w&7, m-pair mh = (w>>3)*2.  TEB swizzle: logical
// 16B-chunk c16 of row r at physical chunk c16^(r&15) (needed: GEMM2 A-frag
// rows stride 3*256B -> 16-way bank conflict without it).
__launch_bounds__(1024, 8)
__global__ void fused_bt(const int* __restrict__ triples,
                         const unsigned short* __restrict__ te_g,
                         const float* __restrict__ b_ht,
                         const float* __restrict__ b_rel,
                         const int* __restrict__ sent_triples,
                         const unsigned char* __restrict__ wsr,
                         float* __restrict__ out) {
  __shared__ unsigned short TEB[192 * 128];    // 48KB: te rows (bf16)
  __shared__ float EWt[8][64];                 // e_weight partials
  __shared__ float PART[8][256];               // wsum partials (8 l-groups)
  __shared__ int MATCH[512];
  __shared__ int NM;

  const int tid  = threadIdx.x;
  const int bt   = blockIdx.x;
  const int w    = tid >> 6;
  const int lane = tid & 63;
  const int li   = lane & 15;
  const int lg   = lane >> 4;
  const int nt   = w & 7;
  const int rh   = w >> 3;

  // tokens per-thread direct (R6-verified broadcast-coalesced pattern)
  int tok[3];
  #pragma unroll
  for (int j = 0; j < 3; ++j) {
    int row = (tid + j * 1024) >> 4;
    tok[j] = triples[(size_t)bt * 192 + row];
  }
  int sidx = -1;
  if (tid < SS) sidx = sent_triples[(size_t)(bt >> 6) * SS + tid];
  if (tid == 0) NM = 0;

  // ---- stage 192 te rows (bf16, 16B/slot — half the old gather bytes) ----
  short8 sv[3];
  #pragma unroll
  for (int j = 0; j < 3; ++j) {
    int o = tid + j * 1024, row = o >> 4, pc = o & 15;
    int clog = pc ^ (row & 15);
    sv[j] = *reinterpret_cast<const short8*>(
        te_g + (size_t)tok[j] * UU + clog * 8);
  }
  #pragma unroll
  for (int j = 0; j < 3; ++j)
    *reinterpret_cast<short8*>(&TEB[(tid + j * 1024) * 8]) = sv[j];

  const unsigned char* whtb = wsr + WHT_OFF;
  const unsigned char* wrlb = wsr + WREL_OFF;
  const float bhv  = b_ht[nt * 16 + li];
  const float brlv = b_rel[nt * 16 + li];
  // prefetch GEMM2 first W-frag before the barrier
  short8 Wc = *reinterpret_cast<const short8*>(
      whtb + (size_t)nt * 1024 + lane * 16);
  __syncthreads();  // (b1) staging complete; NM=0 visible

  // ---- match-find: overlaps GEMM2 (MATCH/NM not read until scatter) ------
  if (sidx == (bt & 63))
    MATCH[atomicAdd(&NM, 1)] = tid;

  // ============ GEMM2: ht_t / rel_t / e_weight (2 m-tiles per wave) =======
  // head = te row 3l+0, rel = 3l+1, tail = 3l+2  (l = m*16 + li)
  const int mh = rh * 2;
  f32x4 accH[2] = {{0.f,0.f,0.f,0.f},{0.f,0.f,0.f,0.f}};
  f32x4 accR[2] = {{0.f,0.f,0.f,0.f},{0.f,0.f,0.f,0.f}};

  #pragma unroll
  for (int kt = 0; kt < 8; ++kt) {   // head_tail: K=256
    short8 Wn;
    if (kt < 7)
      Wn = *reinterpret_cast<const short8*>(
          whtb + (size_t)((kt + 1) * 8 + nt) * 1024 + lane * 16);
    else
      Wn = *reinterpret_cast<const short8*>(
          wrlb + (size_t)nt * 1024 + lane * 16);
    const int koff = (kt < 4) ? 0 : 2;
    const int c16  = (kt & 3) * 4 + lg;
    #pragma unroll
    for (int mi = 0; mi < 2; ++mi) {
      const int row = 48 * (mh + mi) + 3 * li + koff;
      const short8 a = *reinterpret_cast<const short8*>(
          &TEB[row * 128 + ((c16 ^ (row & 15)) << 3)]);
      accH[mi] = __builtin_amdgcn_mfma_f32_16x16x32_bf16(a, Wc, accH[mi], 0, 0, 0);
    }
    Wc = Wn;
  }
  #pragma unroll
  for (int kt = 0; kt < 4; ++kt) {   // relation: K=128, rows 3l+1
    short8 Wn;
    if (kt < 3)
      Wn = *reinterpret_cast<const short8*>(
          wrlb + (size_t)((kt + 1) * 8 + nt) * 1024 + lane * 16);
    const int c16 = kt * 4 + lg;
    #pragma unroll
    for (int mi = 0; mi < 2; ++mi) {
      const int row = 48 * (mh + mi) + 3 * li + 1;
      const short8 a = *reinterpret_cast<const short8*>(
          &TEB[row * 128 + ((c16 ^ (row & 15)) << 3)]);
      accR[mi] = __builtin_amdgcn_mfma_f32_16x16x32_bf16(a, Wc, accR[mi], 0, 0, 0);
    }
    Wc = Wn;
  }

  // e_weight partials: l = (mh+mi)*16 + lg*4 + r; DPP-reduce over 16 u lanes
  #pragma unroll
  for (int mi = 0; mi < 2; ++mi) {
    #pragma unroll
    for (int r = 0; r < 4; ++r) {
      float p = ftanh(accH[mi][r] + bhv) * (accR[mi][r] + brlv);
      p = row16_sum(p);
      if (li == 0) EWt[nt][(mh + mi) * 16 + lg * 4 + r] = p;
    }
  }
  __syncthreads();  // (b2) EWt ready

  // ============ redundant softmax (every wave; no barrier after) ==========
  float alpha;
  {
    float e = 0.f;
    #pragma unroll
    for (int n = 0; n < 8; ++n) e += EWt[n][lane];
    float mx = full64_max(e);
    float ex = __expf(e - mx);
    float sm = full64_sum(ex);
    alpha = ex / sm;
  }

  // ============ weighted sum: paired-bf16 b32 reads, 8 l's per thread ======
  {
    int cp  = tid & 127, lgp = w >> 1;
    int c0  = cp << 1;
    int k   = (c0 >> 7) << 1;              // head rows 3l, tail rows 3l+2
    int cc  = c0 & 127;
    int w8  = cc >> 3, bofs = (cc & 7) << 1;
    float o0 = 0.f, o1 = 0.f;
    #pragma unroll
    for (int j = 0; j < 8; ++j) {
      int l = lgp * 8 + j;
      float al = __int_as_float(
          __builtin_amdgcn_readlane(__float_as_int(alpha), l));
      int row = 3 * l + k;
      unsigned u = *reinterpret_cast<const unsigned*>(
          reinterpret_cast<const char*>(TEB) + row * 256 +
          (((w8 ^ (row & 15)) << 4) | bofs));
      o0 = fmaf(al, __uint_as_float(u << 16), o0);
      o1 = fmaf(al, __uint_as_float(u & 0xFFFF0000u), o1);
    }
    *reinterpret_cast<float2*>(&PART[lgp][c0]) = make_float2(o0, o1);
  }
  __syncthreads();  // (b3) PART ready; MATCH/NM final

  // ============ scatter: participating waves fold the 8-way reduce ========
  {
    const int b  = bt >> 6;
    const int nm = NM;
    if (w < nm) {
      float4 v = {0.f, 0.f, 0.f, 0.f};
      #pragma unroll
      for (int g = 0; g < 8; ++g) {
        float4 p = reinterpret_cast<const float4*>(&PART[g][0])[lane];
        v.x += p.x; v.y += p.y; v.z += p.z; v.w += p.w;
      }
      for (int q = w; q < nm; q += 16) {
        int s = MATCH[q];
        reinterpret_cast<float4*>(out + ((size_t)(b * SS + s)) * 256)[lane] = v;
      }
    }
  }
}

extern "C" void kernel_launch(void* const* d_in, const int* in_sizes, int n_in,
                              void* d_out, int out_size, void* d_ws, size_t ws_size,
                              hipStream_t stream) {
  const int*   triples      = (const int*)d_in[1];
  const int*   sent_triples = (const int*)d_in[2];
  const float* emb_table    = (const float*)d_in[3];
  const float* W_trans      = (const float*)d_in[4];
  const float* b_trans      = (const float*)d_in[5];
  const float* W_ht         = (const float*)d_in[6];
  const float* b_ht         = (const float*)d_in[7];
  const float* W_rel        = (const float*)d_in[8];
  const float* b_rel        = (const float*)d_in[9];
  float* out = (float*)d_out;
  unsigned char* ws = (unsigned char*)d_ws;
  unsigned short* te_g = (unsigned short*)(ws + TE_OFF);

  prep_kernel<<<32, 256, 0, stream>>>(W_trans, W_ht, W_rel, ws);
  prep_te<<<(NV + 191) / 192, 1024, 0, stream>>>(emb_table, b_trans, ws, te_g);
  fused_bt<<<BB * TT, 1024, 0, stream>>>(
      triples, te_g, b_ht, b_rel, sent_triples, ws, out);
}